// Round 1
// baseline (795.901 us; speedup 1.0000x reference)
//
#include <hip/hip_runtime.h>
#include <math.h>

// Problem constants (from reference)
#define NPG   200                 // nodes per graph
#define HDIM  128                 // hidden dim
#define NG    256                 // graphs (B)
#define NT_T  (NG * NPG)          // 51200 total nodes
#define EPG_  3200
#define E_T   (NG * EPG_)         // 819200 total edges
#define ADJ_SZ (NPG * NPG)        // 40000 per-graph adjacency

// ---------------------------------------------------------------------------
// Build per-graph dense adjacency (counts) + per-node in-degree.
// A[g][dst_local][src_local] += 1 ; deg[dst] += 1
// ---------------------------------------------------------------------------
__global__ __launch_bounds__(256) void build_adj_kernel(const int* __restrict__ ei,
                                                        float* __restrict__ A,
                                                        float* __restrict__ deg) {
    int e = blockIdx.x * 256 + threadIdx.x;
    if (e >= E_T) return;
    int src = ei[e];
    int dst = ei[E_T + e];
    int g  = dst / NPG;
    int ls = src - g * NPG;
    int ld = dst - g * NPG;
    atomicAdd(&A[(size_t)g * ADJ_SZ + ld * NPG + ls], 1.0f);
    atomicAdd(&deg[dst], 1.0f);
}

// ---------------------------------------------------------------------------
// C[M,128] = X[M,K] @ W[K,128]. M = 51200 (multiple of 128), K in {200,128}
// (multiple of 8). 128x128 tile, BK=8, 256 threads, 8x8 micro-tile split as
// 4+4 at offset 64 (2-way LDS bank aliasing only -> free).
// ---------------------------------------------------------------------------
__global__ __launch_bounds__(256) void gemm_xw_kernel(const float* __restrict__ X,
                                                      const float* __restrict__ W,
                                                      float* __restrict__ C,
                                                      int K) {
    __shared__ float As[8][128];   // transposed: As[k][row]
    __shared__ float Bs[8][128];   // Bs[k][col]

    const int tid = threadIdx.x;
    const int block_row = blockIdx.x * 128;

    const int a_row = tid >> 1;            // 0..127
    const int a_k   = (tid & 1) * 4;       // 0 or 4
    const int b_row = tid >> 5;            // 0..7
    const int b_col = (tid & 31) * 4;      // 0..124
    const int tr4 = (tid >> 4) * 4;        // 0..60
    const int tc4 = (tid & 15) * 4;        // 0..60

    float acc[8][8];
#pragma unroll
    for (int i = 0; i < 8; ++i)
#pragma unroll
        for (int j = 0; j < 8; ++j) acc[i][j] = 0.0f;

    for (int k0 = 0; k0 < K; k0 += 8) {
        float4 av = *(const float4*)&X[(size_t)(block_row + a_row) * K + k0 + a_k];
        As[a_k + 0][a_row] = av.x;
        As[a_k + 1][a_row] = av.y;
        As[a_k + 2][a_row] = av.z;
        As[a_k + 3][a_row] = av.w;
        *(float4*)&Bs[b_row][b_col] =
            *(const float4*)&W[(size_t)(k0 + b_row) * HDIM + b_col];
        __syncthreads();
#pragma unroll
        for (int kk = 0; kk < 8; ++kk) {
            float4 a0 = *(const float4*)&As[kk][tr4];
            float4 a1 = *(const float4*)&As[kk][tr4 + 64];
            float4 b0 = *(const float4*)&Bs[kk][tc4];
            float4 b1 = *(const float4*)&Bs[kk][tc4 + 64];
            float af[8] = {a0.x, a0.y, a0.z, a0.w, a1.x, a1.y, a1.z, a1.w};
            float bf[8] = {b0.x, b0.y, b0.z, b0.w, b1.x, b1.y, b1.z, b1.w};
#pragma unroll
            for (int i = 0; i < 8; ++i)
#pragma unroll
                for (int j = 0; j < 8; ++j)
                    acc[i][j] = fmaf(af[i], bf[j], acc[i][j]);
        }
        __syncthreads();
    }

#pragma unroll
    for (int i = 0; i < 8; ++i) {
        int r = block_row + ((i < 4) ? (tr4 + i) : (64 + tr4 + i - 4));
        float4 v0 = make_float4(acc[i][0], acc[i][1], acc[i][2], acc[i][3]);
        float4 v1 = make_float4(acc[i][4], acc[i][5], acc[i][6], acc[i][7]);
        *(float4*)&C[(size_t)r * HDIM + tc4]      = v0;
        *(float4*)&C[(size_t)r * HDIM + tc4 + 64] = v1;
    }
}

// ---------------------------------------------------------------------------
// Per-graph aggregation GEMM + GraphConv epilogue:
//   H[g,r,:] = relu( (A[g] @ Trel[g])[r,:] / max(deg,1) + brel + Troot[g,r,:] )
// grid = NG*2 (two 128-row tiles per graph, rows >=200 masked)
// ---------------------------------------------------------------------------
__global__ __launch_bounds__(256) void agg_gemm_kernel(const float* __restrict__ Adj,
                                                       const float* __restrict__ Trel,
                                                       const float* __restrict__ deg,
                                                       const float* __restrict__ brel,
                                                       const float* __restrict__ Troot,
                                                       float* __restrict__ H) {
    __shared__ float As[8][128];
    __shared__ float Bs[8][128];

    const int tid = threadIdx.x;
    const int g = blockIdx.x >> 1;
    const int row0 = (blockIdx.x & 1) * 128;

    const float* Ag = Adj  + (size_t)g * ADJ_SZ;
    const float* Bg = Trel + (size_t)g * NPG * HDIM;

    const int a_row = tid >> 1;
    const int a_k   = (tid & 1) * 4;
    const int b_row = tid >> 5;
    const int b_col = (tid & 31) * 4;
    const int tr4 = (tid >> 4) * 4;
    const int tc4 = (tid & 15) * 4;

    float acc[8][8];
#pragma unroll
    for (int i = 0; i < 8; ++i)
#pragma unroll
        for (int j = 0; j < 8; ++j) acc[i][j] = 0.0f;

    for (int k0 = 0; k0 < NPG; k0 += 8) {
        int ar = row0 + a_row;
        float4 av = make_float4(0.f, 0.f, 0.f, 0.f);
        if (ar < NPG) av = *(const float4*)&Ag[(size_t)ar * NPG + k0 + a_k];
        As[a_k + 0][a_row] = av.x;
        As[a_k + 1][a_row] = av.y;
        As[a_k + 2][a_row] = av.z;
        As[a_k + 3][a_row] = av.w;
        *(float4*)&Bs[b_row][b_col] =
            *(const float4*)&Bg[(size_t)(k0 + b_row) * HDIM + b_col];
        __syncthreads();
#pragma unroll
        for (int kk = 0; kk < 8; ++kk) {
            float4 a0 = *(const float4*)&As[kk][tr4];
            float4 a1 = *(const float4*)&As[kk][tr4 + 64];
            float4 b0 = *(const float4*)&Bs[kk][tc4];
            float4 b1 = *(const float4*)&Bs[kk][tc4 + 64];
            float af[8] = {a0.x, a0.y, a0.z, a0.w, a1.x, a1.y, a1.z, a1.w};
            float bf[8] = {b0.x, b0.y, b0.z, b0.w, b1.x, b1.y, b1.z, b1.w};
#pragma unroll
            for (int i = 0; i < 8; ++i)
#pragma unroll
                for (int j = 0; j < 8; ++j)
                    acc[i][j] = fmaf(af[i], bf[j], acc[i][j]);
        }
        __syncthreads();
    }

#pragma unroll
    for (int i = 0; i < 8; ++i) {
        int lr = row0 + ((i < 4) ? (tr4 + i) : (64 + tr4 + i - 4));
        if (lr < NPG) {
            int grow = g * NPG + lr;
            float inv = 1.0f / fmaxf(deg[grow], 1.0f);
            float o[8];
#pragma unroll
            for (int j = 0; j < 8; ++j) {
                int c = (j < 4) ? (tc4 + j) : (64 + tc4 + j - 4);
                float v = acc[i][j] * inv + brel[c] + Troot[(size_t)grow * HDIM + c];
                o[j] = fmaxf(v, 0.0f);
            }
            *(float4*)&H[(size_t)grow * HDIM + tc4]      = make_float4(o[0], o[1], o[2], o[3]);
            *(float4*)&H[(size_t)grow * HDIM + tc4 + 64] = make_float4(o[4], o[5], o[6], o[7]);
        }
    }
}

// ---------------------------------------------------------------------------
// Readout: z[g, col_off + c] = scale * sum_{n<200} H[g*200+n, c]
// scale = 1/200 -> mean pool (sc), scale = 1 -> add pool (fc)
// ---------------------------------------------------------------------------
__global__ __launch_bounds__(128) void pool_kernel(const float* __restrict__ H,
                                                   float* __restrict__ z,
                                                   int col_off, float scale) {
    int g = blockIdx.x;
    int c = threadIdx.x;
    const float* p = H + (size_t)g * NPG * HDIM + c;
    float s = 0.0f;
    for (int n = 0; n < NPG; ++n) s += p[(size_t)n * HDIM];
    z[(size_t)g * 512 + col_off + c] = s * scale;
}

// ---------------------------------------------------------------------------
// MLP head: z[512] -> relu(lin1) [128] -> relu(lin2) [64] -> lin3 [2] -> log_softmax
// One block (128 threads) per graph.
// ---------------------------------------------------------------------------
__global__ __launch_bounds__(128) void mlp_kernel(const float* __restrict__ z,
                                                  const float* __restrict__ w1, const float* __restrict__ b1,
                                                  const float* __restrict__ w2, const float* __restrict__ b2,
                                                  const float* __restrict__ w3, const float* __restrict__ b3,
                                                  float* __restrict__ out) {
    __shared__ float zs[512];
    __shared__ float l1[128];
    __shared__ float l2[64];
    __shared__ float logits[2];
    int g = blockIdx.x, t = threadIdx.x;

#pragma unroll
    for (int i = 0; i < 4; ++i) zs[t + 128 * i] = z[(size_t)g * 512 + t + 128 * i];
    __syncthreads();

    float s = b1[t];
    for (int k = 0; k < 512; ++k) s = fmaf(zs[k], w1[k * 128 + t], s);
    l1[t] = fmaxf(s, 0.0f);
    __syncthreads();

    if (t < 64) {
        float s2 = b2[t];
        for (int k = 0; k < 128; ++k) s2 = fmaf(l1[k], w2[k * 64 + t], s2);
        l2[t] = fmaxf(s2, 0.0f);
    }
    __syncthreads();

    if (t < 2) {
        float s3 = b3[t];
        for (int k = 0; k < 64; ++k) s3 = fmaf(l2[k], w3[k * 2 + t], s3);
        logits[t] = s3;
    }
    __syncthreads();

    if (t < 2) {
        float m = fmaxf(logits[0], logits[1]);
        float lse = m + logf(expf(logits[0] - m) + expf(logits[1] - m));
        out[(size_t)g * 2 + t] = logits[t] - lse;
    }
}

// ---------------------------------------------------------------------------
extern "C" void kernel_launch(void* const* d_in, const int* in_sizes, int n_in,
                              void* d_out, int out_size, void* d_ws, size_t ws_size,
                              hipStream_t stream) {
    const float* sc_x = (const float*)d_in[0];
    const float* fc_x = (const float*)d_in[1];
    const int* sc_ei  = (const int*)d_in[2];
    const int* fc_ei  = (const int*)d_in[3];
    // d_in[4] = batch (unused: graphs are contiguous 200-node blocks)
    const float* sc1_wrel = (const float*)d_in[5];
    const float* sc1_brel = (const float*)d_in[6];
    const float* sc1_wroot = (const float*)d_in[7];
    const float* sc2_wrel = (const float*)d_in[8];
    const float* sc2_brel = (const float*)d_in[9];
    const float* sc2_wroot = (const float*)d_in[10];
    const float* fc1_wrel = (const float*)d_in[11];
    const float* fc1_brel = (const float*)d_in[12];
    const float* fc1_wroot = (const float*)d_in[13];
    const float* fc2_wrel = (const float*)d_in[14];
    const float* fc2_brel = (const float*)d_in[15];
    const float* fc2_wroot = (const float*)d_in[16];
    const float* lin1_w = (const float*)d_in[17];
    const float* lin1_b = (const float*)d_in[18];
    const float* lin2_w = (const float*)d_in[19];
    const float* lin2_b = (const float*)d_in[20];
    const float* lin3_w = (const float*)d_in[21];
    const float* lin3_b = (const float*)d_in[22];

    // Workspace layout (floats): A | trel | troot | h | deg | z  (~120.4 MB)
    float* ws    = (float*)d_ws;
    float* A     = ws;                                  // 10,240,000
    float* trel  = A + (size_t)NG * ADJ_SZ;             //  6,553,600
    float* troot = trel + (size_t)NT_T * HDIM;          //  6,553,600
    float* h     = troot + (size_t)NT_T * HDIM;         //  6,553,600
    float* deg   = h + (size_t)NT_T * HDIM;             //     51,200
    float* z     = deg + NT_T;                          //    131,072

    struct BranchP {
        const float* x; const int* ei;
        const float* w1r; const float* b1; const float* w1o;
        const float* w2r; const float* b2; const float* w2o;
        int zoff; float scale;
    };
    BranchP branches[2] = {
        { sc_x, sc_ei, sc1_wrel, sc1_brel, sc1_wroot, sc2_wrel, sc2_brel, sc2_wroot, 0,   1.0f / 200.0f },
        { fc_x, fc_ei, fc1_wrel, fc1_brel, fc1_wroot, fc2_wrel, fc2_brel, fc2_wroot, 256, 1.0f          },
    };

    for (int bi = 0; bi < 2; ++bi) {
        BranchP& p = branches[bi];
        hipMemsetAsync(A, 0, (size_t)NG * ADJ_SZ * sizeof(float), stream);
        hipMemsetAsync(deg, 0, (size_t)NT_T * sizeof(float), stream);
        build_adj_kernel<<<(E_T + 255) / 256, 256, 0, stream>>>(p.ei, A, deg);

        // Layer 1: K = 200
        gemm_xw_kernel<<<NT_T / 128, 256, 0, stream>>>(p.x, p.w1r, trel, 200);
        gemm_xw_kernel<<<NT_T / 128, 256, 0, stream>>>(p.x, p.w1o, troot, 200);
        agg_gemm_kernel<<<NG * 2, 256, 0, stream>>>(A, trel, deg, p.b1, troot, h);
        pool_kernel<<<NG, 128, 0, stream>>>(h, z, p.zoff, p.scale);

        // Layer 2: K = 128
        gemm_xw_kernel<<<NT_T / 128, 256, 0, stream>>>(h, p.w2r, trel, 128);
        gemm_xw_kernel<<<NT_T / 128, 256, 0, stream>>>(h, p.w2o, troot, 128);
        agg_gemm_kernel<<<NG * 2, 256, 0, stream>>>(A, trel, deg, p.b2, troot, h);
        pool_kernel<<<NG, 128, 0, stream>>>(h, z, p.zoff + 128, p.scale);
    }

    mlp_kernel<<<NG, 128, 0, stream>>>(z, lin1_w, lin1_b, lin2_w, lin2_b,
                                       lin3_w, lin3_b, (float*)d_out);
}

// Round 2
// 427.072 us; speedup vs baseline: 1.8636x; 1.8636x over previous
//
#include <hip/hip_runtime.h>
#include <math.h>

#define NPG   200                 // nodes per graph
#define HDIM  128
#define NG    256
#define NT_T  (NG * NPG)          // 51200
#define EPG_  3200
#define E_T   (NG * EPG_)         // 819200
#define KP1   224                 // layer-1 K (200) padded to mult of 32
#define APITCH 224                // A' row pitch (src dim padded)
#define TP    51264               // T^T node pitch (51200 + 64 pad)

typedef short short8 __attribute__((ext_vector_type(8)));
typedef float f32x4  __attribute__((ext_vector_type(4)));

__device__ __forceinline__ unsigned short f2bf(float f) {
    union { float f; unsigned int u; } v; v.f = f;
    unsigned int u = v.u;
    u += 0x7FFFu + ((u >> 16) & 1u);       // round-to-nearest-even
    return (unsigned short)(u >> 16);
}
__device__ __forceinline__ float bf2f(unsigned short b) {
    union { unsigned int u; float f; } v; v.u = ((unsigned int)b) << 16;
    return v.f;
}

// ---------------------------------------------------------------------------
// Per-graph adjacency via LDS u8 counters; output A' = count/max(deg,1) in
// bf16, layout [g][dst 0..199][src 0..223] (src>=200 zero-padded).
// One block per graph.
// ---------------------------------------------------------------------------
__global__ __launch_bounds__(256) void build_adj_kernel(const int* __restrict__ ei,
                                                        unsigned short* __restrict__ A) {
    __shared__ unsigned int cnt[10000];    // 200*200 u8 counters packed in u32
    __shared__ float invdeg[200];
    const int g = blockIdx.x, t = threadIdx.x;

    for (int i = t; i < 10000; i += 256) cnt[i] = 0u;
    __syncthreads();

    const int ebase = g * EPG_;
    for (int i = t; i < EPG_; i += 256) {
        int src = ei[ebase + i];
        int dst = ei[E_T + ebase + i];
        int idx = (dst - g * NPG) * NPG + (src - g * NPG);
        atomicAdd(&cnt[idx >> 2], 1u << ((idx & 3) * 8));
    }
    __syncthreads();

    if (t < NPG) {
        unsigned int s = 0;
        for (int w = 0; w < 50; ++w) {
            unsigned int v = cnt[t * 50 + w];
            s += (v & 0xFFu) + ((v >> 8) & 0xFFu) + ((v >> 16) & 0xFFu) + ((v >> 24) & 0xFFu);
        }
        invdeg[t] = 1.0f / fmaxf((float)s, 1.0f);
    }
    __syncthreads();

    unsigned short* Ag = A + (size_t)g * NPG * APITCH;
    for (int q = t; q < NPG * (APITCH / 4); q += 256) {   // 200*56 quads of 4
        int row = q / 56;
        int c4  = (q - row * 56) * 4;
        float inv = invdeg[row];
        ushort4 o;
        unsigned short* po = (unsigned short*)&o;
#pragma unroll
        for (int j = 0; j < 4; ++j) {
            int col = c4 + j;
            float v = 0.0f;
            if (col < NPG) {
                unsigned int w = cnt[row * 50 + (col >> 2)];
                v = (float)((w >> ((col & 3) * 8)) & 0xFFu) * inv;
            }
            po[j] = f2bf(v);
        }
        *(ushort4*)&Ag[row * APITCH + c4] = o;
    }
}

// ---------------------------------------------------------------------------
// fp32 [NT,200] -> bf16 [NT,224] (k>=200 zero). One 8-elem chunk per thread.
// ---------------------------------------------------------------------------
__global__ __launch_bounds__(256) void convert_x_kernel(const float* __restrict__ x,
                                                        unsigned short* __restrict__ xb) {
    int c = blockIdx.x * 256 + threadIdx.x;       // chunk id, 28 chunks/node
    if (c >= NT_T * 28) return;
    int node = c / 28;
    int koff = (c - node * 28) * 8;
    uint4 o;
    if (koff < 200) {
        const float* p = x + (size_t)node * 200 + koff;
        float4 a = *(const float4*)p;
        float4 b = *(const float4*)(p + 4);
        o.x = (unsigned)f2bf(a.x) | ((unsigned)f2bf(a.y) << 16);
        o.y = (unsigned)f2bf(a.z) | ((unsigned)f2bf(a.w) << 16);
        o.z = (unsigned)f2bf(b.x) | ((unsigned)f2bf(b.y) << 16);
        o.w = (unsigned)f2bf(b.z) | ((unsigned)f2bf(b.w) << 16);
    } else {
        o.x = o.y = o.z = o.w = 0u;
    }
    *(uint4*)&xb[(size_t)node * KP1 + koff] = o;
}

// ---------------------------------------------------------------------------
// Pack [wrel | wroot] (each [K,128] fp32) into W^T bf16 [256][Kp] (k>=K zero).
// ---------------------------------------------------------------------------
__global__ __launch_bounds__(256) void convert_w_kernel(const float* __restrict__ wrel,
                                                        const float* __restrict__ wroot,
                                                        unsigned short* __restrict__ wb,
                                                        int K, int Kp) {
    int idx = blockIdx.x * 256 + threadIdx.x;
    if (idx >= 256 * Kp) return;
    int c = idx / Kp, k = idx - c * Kp;
    float v = 0.0f;
    if (k < K) v = (c < 128) ? wrel[(size_t)k * 128 + c] : wroot[(size_t)k * 128 + (c - 128)];
    wb[idx] = f2bf(v);
}

// ---------------------------------------------------------------------------
// Transform GEMM: T^T[n0+c][node] = sum_k X[node][k] * W[c][k]  (bf16 MFMA)
// X: [51200][K] bf16 row-major, W: [256][K] bf16 (pre-transposed),
// out: T^T [256][TP] bf16. Block tile 128x128, 4 waves in 2x2, wave 64x64.
// grid: (400, 2).
// ---------------------------------------------------------------------------
__global__ __launch_bounds__(256) void gemm_t_kernel(const unsigned short* __restrict__ X,
                                                     const unsigned short* __restrict__ W,
                                                     unsigned short* __restrict__ Tt,
                                                     int K) {
    __shared__ short As[128 * 40];   // [row][k] stride 40 (80B, conflict-free)
    __shared__ short Bs[128 * 40];   // [col][k]

    const int tid = threadIdx.x;
    const int lane = tid & 63, wid = tid >> 6;
    const int wm = (wid & 1) * 64, wn = (wid >> 1) * 64;
    const int l15 = lane & 15, quad = lane >> 4;
    const size_t block_row = (size_t)blockIdx.x * 128;
    const int n0 = blockIdx.y * 128;

    f32x4 acc[4][4];
#pragma unroll
    for (int m = 0; m < 4; ++m)
#pragma unroll
        for (int n = 0; n < 4; ++n)
#pragma unroll
            for (int r = 0; r < 4; ++r) acc[m][n][r] = 0.0f;

    const int r0 = tid >> 2, k0off = (tid & 3) * 8;          // chunk 0
    const int r1 = (tid + 256) >> 2, k1off = ((tid + 256) & 3) * 8;

    for (int k0 = 0; k0 < K; k0 += 32) {
        *(uint4*)&As[r0 * 40 + k0off] = *(const uint4*)&X[(block_row + r0) * K + k0 + k0off];
        *(uint4*)&As[r1 * 40 + k1off] = *(const uint4*)&X[(block_row + r1) * K + k0 + k1off];
        *(uint4*)&Bs[r0 * 40 + k0off] = *(const uint4*)&W[(size_t)(n0 + r0) * K + k0 + k0off];
        *(uint4*)&Bs[r1 * 40 + k1off] = *(const uint4*)&W[(size_t)(n0 + r1) * K + k0 + k1off];
        __syncthreads();

        short8 af[4], bf[4];
#pragma unroll
        for (int m = 0; m < 4; ++m)
            af[m] = *(const short8*)&As[(wm + m * 16 + l15) * 40 + quad * 8];
#pragma unroll
        for (int n = 0; n < 4; ++n)
            bf[n] = *(const short8*)&Bs[(wn + n * 16 + l15) * 40 + quad * 8];
#pragma unroll
        for (int m = 0; m < 4; ++m)
#pragma unroll
            for (int n = 0; n < 4; ++n)
                acc[m][n] = __builtin_amdgcn_mfma_f32_16x16x32_bf16(af[m], bf[n], acc[m][n], 0, 0, 0);
        __syncthreads();
    }

    // Epilogue: D row=(quad*4+r) -> node, col=l15 -> output channel
#pragma unroll
    for (int m = 0; m < 4; ++m) {
#pragma unroll
        for (int n = 0; n < 4; ++n) {
            int col = n0 + wn + n * 16 + l15;
            size_t node = block_row + wm + m * 16 + quad * 4;
            ushort4 o;
            unsigned short* po = (unsigned short*)&o;
#pragma unroll
            for (int r = 0; r < 4; ++r) po[r] = f2bf(acc[m][n][r]);
            *(ushort4*)&Tt[(size_t)col * TP + node] = o;
        }
    }
}

// ---------------------------------------------------------------------------
// Agg GEMM + GraphConv epilogue (bf16 MFMA):
//   H[g*200+d][c] = relu( (A'[g] @ Trel[g])[d][c] + brel[c] + Troot[d][c] )
// A': [g][200][224] bf16 (deg-scaled), Trel = T^T rows 0..127, Troot rows 128..255.
// grid: 512 = g*2 (two 128-row tiles; rows>=200 masked).
// ---------------------------------------------------------------------------
__global__ __launch_bounds__(256) void gemm_agg_kernel(const unsigned short* __restrict__ A,
                                                       const unsigned short* __restrict__ Tt,
                                                       const float* __restrict__ brel,
                                                       unsigned short* __restrict__ H) {
    __shared__ short As[128 * 40];
    __shared__ short Bs[128 * 40];

    const int tid = threadIdx.x;
    const int lane = tid & 63, wid = tid >> 6;
    const int wm = (wid & 1) * 64, wn = (wid >> 1) * 64;
    const int l15 = lane & 15, quad = lane >> 4;
    const int g = blockIdx.x >> 1;
    const int row0 = (blockIdx.x & 1) * 128;
    const unsigned short* Ag = A + (size_t)g * NPG * APITCH;
    const size_t gnode = (size_t)g * NPG;

    f32x4 acc[4][4];
#pragma unroll
    for (int m = 0; m < 4; ++m)
#pragma unroll
        for (int n = 0; n < 4; ++n)
#pragma unroll
            for (int r = 0; r < 4; ++r) acc[m][n][r] = 0.0f;

    const int r0 = tid >> 2, k0off = (tid & 3) * 8;
    const int r1 = (tid + 256) >> 2, k1off = ((tid + 256) & 3) * 8;

    for (int k0 = 0; k0 < KP1; k0 += 32) {
        uint4 z4; z4.x = z4.y = z4.z = z4.w = 0u;
        uint4 v0 = z4, v1 = z4;
        if (row0 + r0 < NPG) v0 = *(const uint4*)&Ag[(row0 + r0) * APITCH + k0 + k0off];
        if (row0 + r1 < NPG) v1 = *(const uint4*)&Ag[(row0 + r1) * APITCH + k0 + k1off];
        *(uint4*)&As[r0 * 40 + k0off] = v0;
        *(uint4*)&As[r1 * 40 + k1off] = v1;
        // B: Bs[col][k] from T^T[col][g*200 + k]  (k beyond graph is multiplied by A'=0)
        *(uint4*)&Bs[r0 * 40 + k0off] = *(const uint4*)&Tt[(size_t)r0 * TP + gnode + k0 + k0off];
        *(uint4*)&Bs[r1 * 40 + k1off] = *(const uint4*)&Tt[(size_t)r1 * TP + gnode + k0 + k1off];
        __syncthreads();

        short8 af[4], bf[4];
#pragma unroll
        for (int m = 0; m < 4; ++m)
            af[m] = *(const short8*)&As[(wm + m * 16 + l15) * 40 + quad * 8];
#pragma unroll
        for (int n = 0; n < 4; ++n)
            bf[n] = *(const short8*)&Bs[(wn + n * 16 + l15) * 40 + quad * 8];
#pragma unroll
        for (int m = 0; m < 4; ++m)
#pragma unroll
            for (int n = 0; n < 4; ++n)
                acc[m][n] = __builtin_amdgcn_mfma_f32_16x16x32_bf16(af[m], bf[n], acc[m][n], 0, 0, 0);
        __syncthreads();
    }

#pragma unroll
    for (int m = 0; m < 4; ++m) {
        int gr = row0 + wm + m * 16 + quad * 4;
        if (gr >= NPG) continue;
        size_t nodeb = gnode + gr;
#pragma unroll
        for (int n = 0; n < 4; ++n) {
            int c = wn + n * 16 + l15;
            ushort4 rt = *(const ushort4*)&Tt[(size_t)(128 + c) * TP + nodeb];
            const unsigned short* prt = (const unsigned short*)&rt;
            float bb = brel[c];
#pragma unroll
            for (int r = 0; r < 4; ++r) {
                float v = acc[m][n][r] + bb + bf2f(prt[r]);
                H[(nodeb + r) * HDIM + c] = f2bf(fmaxf(v, 0.0f));
            }
        }
    }
}

// ---------------------------------------------------------------------------
// Readout: z[g, col_off + c] = scale * sum_n H[g*200+n, c]   (H bf16)
// ---------------------------------------------------------------------------
__global__ __launch_bounds__(128) void pool_kernel(const unsigned short* __restrict__ H,
                                                   float* __restrict__ z,
                                                   int col_off, float scale) {
    int g = blockIdx.x, c = threadIdx.x;
    const unsigned short* p = H + (size_t)g * NPG * HDIM + c;
    float s = 0.0f;
    for (int n = 0; n < NPG; ++n) s += bf2f(p[(size_t)n * HDIM]);
    z[(size_t)g * 512 + col_off + c] = s * scale;
}

// ---------------------------------------------------------------------------
// MLP head (fp32): z[512] -> relu(lin1)[128] -> relu(lin2)[64] -> lin3[2]
// -> log_softmax. One block per graph.
// ---------------------------------------------------------------------------
__global__ __launch_bounds__(128) void mlp_kernel(const float* __restrict__ z,
                                                  const float* __restrict__ w1, const float* __restrict__ b1,
                                                  const float* __restrict__ w2, const float* __restrict__ b2,
                                                  const float* __restrict__ w3, const float* __restrict__ b3,
                                                  float* __restrict__ out) {
    __shared__ float zs[512];
    __shared__ float l1[128];
    __shared__ float l2[64];
    __shared__ float logits[2];
    int g = blockIdx.x, t = threadIdx.x;

#pragma unroll
    for (int i = 0; i < 4; ++i) zs[t + 128 * i] = z[(size_t)g * 512 + t + 128 * i];
    __syncthreads();

    float s = b1[t];
    for (int k = 0; k < 512; ++k) s = fmaf(zs[k], w1[k * 128 + t], s);
    l1[t] = fmaxf(s, 0.0f);
    __syncthreads();

    if (t < 64) {
        float s2 = b2[t];
        for (int k = 0; k < 128; ++k) s2 = fmaf(l1[k], w2[k * 64 + t], s2);
        l2[t] = fmaxf(s2, 0.0f);
    }
    __syncthreads();

    if (t < 2) {
        float s3 = b3[t];
        for (int k = 0; k < 64; ++k) s3 = fmaf(l2[k], w3[k * 2 + t], s3);
        logits[t] = s3;
    }
    __syncthreads();

    if (t < 2) {
        float m = fmaxf(logits[0], logits[1]);
        float lse = m + logf(expf(logits[0] - m) + expf(logits[1] - m));
        out[(size_t)g * 2 + t] = logits[t] - lse;
    }
}

// ---------------------------------------------------------------------------
extern "C" void kernel_launch(void* const* d_in, const int* in_sizes, int n_in,
                              void* d_out, int out_size, void* d_ws, size_t ws_size,
                              hipStream_t stream) {
    const float* sc_x = (const float*)d_in[0];
    const float* fc_x = (const float*)d_in[1];
    const int* sc_ei  = (const int*)d_in[2];
    const int* fc_ei  = (const int*)d_in[3];
    const float* sc1_wrel = (const float*)d_in[5];
    const float* sc1_brel = (const float*)d_in[6];
    const float* sc1_wroot = (const float*)d_in[7];
    const float* sc2_wrel = (const float*)d_in[8];
    const float* sc2_brel = (const float*)d_in[9];
    const float* sc2_wroot = (const float*)d_in[10];
    const float* fc1_wrel = (const float*)d_in[11];
    const float* fc1_brel = (const float*)d_in[12];
    const float* fc1_wroot = (const float*)d_in[13];
    const float* fc2_wrel = (const float*)d_in[14];
    const float* fc2_brel = (const float*)d_in[15];
    const float* fc2_wroot = (const float*)d_in[16];
    const float* lin1_w = (const float*)d_in[17];
    const float* lin1_b = (const float*)d_in[18];
    const float* lin2_w = (const float*)d_in[19];
    const float* lin2_b = (const float*)d_in[20];
    const float* lin3_w = (const float*)d_in[21];
    const float* lin3_b = (const float*)d_in[22];

    // Workspace layout (bf16/ushort unless noted), all 16B-aligned blocks:
    unsigned short* Xb = (unsigned short*)d_ws;                 // 51200*224
    unsigned short* Ab = Xb + (size_t)NT_T * KP1;               // 256*200*224
    unsigned short* Tt = Ab + (size_t)NG * NPG * APITCH;        // 256*TP
    unsigned short* h  = Tt + (size_t)256 * TP;                 // 51200*128
    unsigned short* Wb = h + (size_t)NT_T * HDIM;               // 256*224
    float* z = (float*)(Wb + (size_t)256 * KP1);                // 256*512 fp32

    struct BranchP {
        const float* x; const int* ei;
        const float* w1r; const float* b1; const float* w1o;
        const float* w2r; const float* b2; const float* w2o;
        int zoff; float scale;
    };
    BranchP branches[2] = {
        { sc_x, sc_ei, sc1_wrel, sc1_brel, sc1_wroot, sc2_wrel, sc2_brel, sc2_wroot, 0,   1.0f / 200.0f },
        { fc_x, fc_ei, fc1_wrel, fc1_brel, fc1_wroot, fc2_wrel, fc2_brel, fc2_wroot, 256, 1.0f          },
    };

    for (int bi = 0; bi < 2; ++bi) {
        BranchP& p = branches[bi];
        build_adj_kernel<<<NG, 256, 0, stream>>>(p.ei, Ab);
        convert_x_kernel<<<(NT_T * 28 + 255) / 256, 256, 0, stream>>>(p.x, Xb);
        convert_w_kernel<<<(256 * KP1 + 255) / 256, 256, 0, stream>>>(p.w1r, p.w1o, Wb, 200, KP1);

        // Layer 1
        gemm_t_kernel<<<dim3(NT_T / 128, 2), 256, 0, stream>>>(Xb, Wb, Tt, KP1);
        gemm_agg_kernel<<<NG * 2, 256, 0, stream>>>(Ab, Tt, p.b1, h);
        pool_kernel<<<NG, 128, 0, stream>>>(h, z, p.zoff, p.scale);

        // Layer 2
        convert_w_kernel<<<(256 * HDIM + 255) / 256, 256, 0, stream>>>(p.w2r, p.w2o, Wb, 128, 128);
        gemm_t_kernel<<<dim3(NT_T / 128, 2), 256, 0, stream>>>(h, Wb, Tt, 128);
        gemm_agg_kernel<<<NG * 2, 256, 0, stream>>>(Ab, Tt, p.b2, h);
        pool_kernel<<<NG, 128, 0, stream>>>(h, z, p.zoff + 128, p.scale);
    }

    mlp_kernel<<<NG, 128, 0, stream>>>(z, lin1_w, lin1_b, lin2_w, lin2_b,
                                       lin3_w, lin3_b, (float*)d_out);
}

// Round 3
// 392.137 us; speedup vs baseline: 2.0296x; 1.0891x over previous
//
#include <hip/hip_runtime.h>
#include <math.h>

#define NPG   200                 // nodes per graph
#define HDIM  128
#define NG    256
#define NT_T  (NG * NPG)          // 51200
#define EPG_  3200
#define E_T   (NG * EPG_)         // 819200
#define KP1   224                 // layer-1 K (200) padded to mult of 32
#define APITCH 224                // A' row pitch
#define TP    51264               // T^T node pitch (51200 + 64 pad)
#define W1SZ  (256 * KP1)         // 57344 shorts per branch (layer-1 packed W)
#define W2SZ  (256 * HDIM)        // 32768 shorts per branch (layer-2 packed W)

typedef short short8 __attribute__((ext_vector_type(8)));
typedef float f32x4  __attribute__((ext_vector_type(4)));

__device__ __forceinline__ unsigned short f2bf(float f) {
    union { float f; unsigned int u; } v; v.f = f;
    unsigned int u = v.u;
    u += 0x7FFFu + ((u >> 16) & 1u);       // RNE
    return (unsigned short)(u >> 16);
}
__device__ __forceinline__ float bf2f(unsigned short b) {
    union { unsigned int u; float f; } v; v.u = ((unsigned int)b) << 16;
    return v.f;
}

// ---------------------------------------------------------------------------
// Both branches: per-graph adjacency via LDS u8 counters ->
// A' = count/max(deg,1) bf16, [branch][g][dst 0..199][src 0..223].
// grid = 512 (branch = blockIdx.x>>8).
// ---------------------------------------------------------------------------
__global__ __launch_bounds__(256) void build_adj_kernel(const int* __restrict__ sc_ei,
                                                        const int* __restrict__ fc_ei,
                                                        unsigned short* __restrict__ A) {
    __shared__ unsigned int cnt[10000];    // 200*200 u8 counters packed in u32
    __shared__ float invdeg[200];
    const int branch = blockIdx.x >> 8;
    const int g = blockIdx.x & 255, t = threadIdx.x;
    const int* ei = branch ? fc_ei : sc_ei;

    for (int i = t; i < 10000; i += 256) cnt[i] = 0u;
    __syncthreads();

    const int ebase = g * EPG_;
    for (int i = t; i < EPG_; i += 256) {
        int src = ei[ebase + i];
        int dst = ei[E_T + ebase + i];
        int idx = (dst - g * NPG) * NPG + (src - g * NPG);
        atomicAdd(&cnt[idx >> 2], 1u << ((idx & 3) * 8));
    }
    __syncthreads();

    if (t < NPG) {
        unsigned int s = 0;
        for (int w = 0; w < 50; ++w) {
            unsigned int v = cnt[t * 50 + w];
            s += (v & 0xFFu) + ((v >> 8) & 0xFFu) + ((v >> 16) & 0xFFu) + ((v >> 24) & 0xFFu);
        }
        invdeg[t] = 1.0f / fmaxf((float)s, 1.0f);
    }
    __syncthreads();

    unsigned short* Ag = A + ((size_t)branch * NG + g) * NPG * APITCH;
    for (int q = t; q < NPG * (APITCH / 4); q += 256) {   // 200*56 quads
        int row = q / 56;
        int c4  = (q - row * 56) * 4;
        float inv = invdeg[row];
        ushort4 o;
        unsigned short* po = (unsigned short*)&o;
#pragma unroll
        for (int j = 0; j < 4; ++j) {
            int col = c4 + j;
            float v = 0.0f;
            if (col < NPG) {
                unsigned int w = cnt[row * 50 + (col >> 2)];
                v = (float)((w >> ((col & 3) * 8)) & 0xFFu) * inv;
            }
            po[j] = f2bf(v);
        }
        *(ushort4*)&Ag[row * APITCH + c4] = o;
    }
}

// ---------------------------------------------------------------------------
// All 4 weight pairs -> packed W^T bf16 in one launch.
// Layout: [br0 L1 | br1 L1 | br0 L2 | br1 L2], L1 pitch 224 (k>=200 zero),
// L2 pitch 128. Rows 0..127 = wrel cols, 128..255 = wroot cols.
// ---------------------------------------------------------------------------
__global__ __launch_bounds__(256) void convert_w_kernel(
        const float* __restrict__ s1r, const float* __restrict__ s1o,
        const float* __restrict__ f1r, const float* __restrict__ f1o,
        const float* __restrict__ s2r, const float* __restrict__ s2o,
        const float* __restrict__ f2r, const float* __restrict__ f2o,
        unsigned short* __restrict__ wb) {
    int idx = blockIdx.x * 256 + threadIdx.x;
    if (idx >= 2 * W1SZ + 2 * W2SZ) return;
    float v = 0.0f;
    if (idx < 2 * W1SZ) {
        int branch = idx / W1SZ, rem = idx - branch * W1SZ;
        int c = rem / KP1, k = rem - c * KP1;
        const float* wr = branch ? f1r : s1r;
        const float* wo = branch ? f1o : s1o;
        if (k < 200) v = (c < 128) ? wr[(size_t)k * 128 + c] : wo[(size_t)k * 128 + (c - 128)];
    } else {
        int i2 = idx - 2 * W1SZ;
        int branch = i2 / W2SZ, rem = i2 - branch * W2SZ;
        int c = rem / HDIM, k = rem - c * HDIM;
        const float* wr = branch ? f2r : s2r;
        const float* wo = branch ? f2o : s2o;
        v = (c < 128) ? wr[(size_t)k * 128 + c] : wo[(size_t)k * 128 + (c - 128)];
    }
    wb[idx] = f2bf(v);
}

// ---------------------------------------------------------------------------
// Layer-1 transform GEMM, fp32 X (fused convert): T^T[c][node] = X@[Wrel|Wroot]
// grid (400, 2, 2): x=row tile, y=col tile, z=branch.
// ---------------------------------------------------------------------------
__global__ __launch_bounds__(256) void gemm_t1_kernel(const float* __restrict__ sc_x,
                                                      const float* __restrict__ fc_x,
                                                      const unsigned short* __restrict__ Wall,
                                                      unsigned short* __restrict__ Tt) {
    __shared__ short As[128 * 40];   // [row][k], stride 40 shorts (80B)
    __shared__ short Bs[128 * 40];   // [col][k]

    const int tid = threadIdx.x;
    const int lane = tid & 63, wid = tid >> 6;
    const int wm = (wid & 1) * 64, wn = (wid >> 1) * 64;
    const int l15 = lane & 15, quad = lane >> 4;
    const size_t block_row = (size_t)blockIdx.x * 128;
    const int n0 = blockIdx.y * 128;
    const int branch = blockIdx.z;
    const float* X = branch ? fc_x : sc_x;
    const unsigned short* W = Wall + (size_t)branch * W1SZ;
    unsigned short* Ttb = Tt + (size_t)branch * 256 * TP;

    f32x4 acc[4][4];
#pragma unroll
    for (int m = 0; m < 4; ++m)
#pragma unroll
        for (int n = 0; n < 4; ++n)
#pragma unroll
            for (int r = 0; r < 4; ++r) acc[m][n][r] = 0.0f;

    const int r0 = tid >> 2, k0off = (tid & 3) * 8;
    const int r1 = (tid + 256) >> 2, k1off = ((tid + 256) & 3) * 8;

    for (int k0 = 0; k0 < KP1; k0 += 32) {
        // X (fp32) -> bf16 pack -> LDS. Chunks are 8-aligned; 200 % 8 == 0 so
        // each 8-chunk is fully valid or fully padded.
        uint4 pk[2];
#pragma unroll
        for (int c = 0; c < 2; ++c) {
            int rr = c ? r1 : r0;
            int kk = k0 + (c ? k1off : k0off);
            uint4 o;
            if (kk < 200) {
                const float* p = X + (size_t)(block_row + rr) * 200 + kk;
                float4 a = *(const float4*)p;
                float4 b = *(const float4*)(p + 4);
                o.x = (unsigned)f2bf(a.x) | ((unsigned)f2bf(a.y) << 16);
                o.y = (unsigned)f2bf(a.z) | ((unsigned)f2bf(a.w) << 16);
                o.z = (unsigned)f2bf(b.x) | ((unsigned)f2bf(b.y) << 16);
                o.w = (unsigned)f2bf(b.z) | ((unsigned)f2bf(b.w) << 16);
            } else {
                o.x = o.y = o.z = o.w = 0u;
            }
            pk[c] = o;
        }
        *(uint4*)&As[r0 * 40 + k0off] = pk[0];
        *(uint4*)&As[r1 * 40 + k1off] = pk[1];
        *(uint4*)&Bs[r0 * 40 + k0off] = *(const uint4*)&W[(size_t)(n0 + r0) * KP1 + k0 + k0off];
        *(uint4*)&Bs[r1 * 40 + k1off] = *(const uint4*)&W[(size_t)(n0 + r1) * KP1 + k0 + k1off];
        __syncthreads();

        short8 af[4], bf[4];
#pragma unroll
        for (int m = 0; m < 4; ++m)
            af[m] = *(const short8*)&As[(wm + m * 16 + l15) * 40 + quad * 8];
#pragma unroll
        for (int n = 0; n < 4; ++n)
            bf[n] = *(const short8*)&Bs[(wn + n * 16 + l15) * 40 + quad * 8];
#pragma unroll
        for (int m = 0; m < 4; ++m)
#pragma unroll
            for (int n = 0; n < 4; ++n)
                acc[m][n] = __builtin_amdgcn_mfma_f32_16x16x32_bf16(af[m], bf[n], acc[m][n], 0, 0, 0);
        __syncthreads();
    }

#pragma unroll
    for (int m = 0; m < 4; ++m) {
#pragma unroll
        for (int n = 0; n < 4; ++n) {
            int col = n0 + wn + n * 16 + l15;
            size_t node = block_row + wm + m * 16 + quad * 4;
            ushort4 o;
            unsigned short* po = (unsigned short*)&o;
#pragma unroll
            for (int r = 0; r < 4; ++r) po[r] = f2bf(acc[m][n][r]);
            *(ushort4*)&Ttb[(size_t)col * TP + node] = o;
        }
    }
}

// ---------------------------------------------------------------------------
// Layer-2 transform GEMM, bf16 X (= h). grid (400, 2, 2).
// ---------------------------------------------------------------------------
__global__ __launch_bounds__(256) void gemm_t2_kernel(const unsigned short* __restrict__ Hin,
                                                      const unsigned short* __restrict__ Wall,
                                                      unsigned short* __restrict__ Tt) {
    __shared__ short As[128 * 40];
    __shared__ short Bs[128 * 40];

    const int tid = threadIdx.x;
    const int lane = tid & 63, wid = tid >> 6;
    const int wm = (wid & 1) * 64, wn = (wid >> 1) * 64;
    const int l15 = lane & 15, quad = lane >> 4;
    const size_t block_row = (size_t)blockIdx.x * 128;
    const int n0 = blockIdx.y * 128;
    const int branch = blockIdx.z;
    const unsigned short* X = Hin + (size_t)branch * NT_T * HDIM;
    const unsigned short* W = Wall + 2 * W1SZ + (size_t)branch * W2SZ;
    unsigned short* Ttb = Tt + (size_t)branch * 256 * TP;

    f32x4 acc[4][4];
#pragma unroll
    for (int m = 0; m < 4; ++m)
#pragma unroll
        for (int n = 0; n < 4; ++n)
#pragma unroll
            for (int r = 0; r < 4; ++r) acc[m][n][r] = 0.0f;

    const int r0 = tid >> 2, k0off = (tid & 3) * 8;
    const int r1 = (tid + 256) >> 2, k1off = ((tid + 256) & 3) * 8;

    for (int k0 = 0; k0 < HDIM; k0 += 32) {
        *(uint4*)&As[r0 * 40 + k0off] = *(const uint4*)&X[(block_row + r0) * HDIM + k0 + k0off];
        *(uint4*)&As[r1 * 40 + k1off] = *(const uint4*)&X[(block_row + r1) * HDIM + k0 + k1off];
        *(uint4*)&Bs[r0 * 40 + k0off] = *(const uint4*)&W[(size_t)(n0 + r0) * HDIM + k0 + k0off];
        *(uint4*)&Bs[r1 * 40 + k1off] = *(const uint4*)&W[(size_t)(n0 + r1) * HDIM + k0 + k1off];
        __syncthreads();

        short8 af[4], bf[4];
#pragma unroll
        for (int m = 0; m < 4; ++m)
            af[m] = *(const short8*)&As[(wm + m * 16 + l15) * 40 + quad * 8];
#pragma unroll
        for (int n = 0; n < 4; ++n)
            bf[n] = *(const short8*)&Bs[(wn + n * 16 + l15) * 40 + quad * 8];
#pragma unroll
        for (int m = 0; m < 4; ++m)
#pragma unroll
            for (int n = 0; n < 4; ++n)
                acc[m][n] = __builtin_amdgcn_mfma_f32_16x16x32_bf16(af[m], bf[n], acc[m][n], 0, 0, 0);
        __syncthreads();
    }

#pragma unroll
    for (int m = 0; m < 4; ++m) {
#pragma unroll
        for (int n = 0; n < 4; ++n) {
            int col = n0 + wn + n * 16 + l15;
            size_t node = block_row + wm + m * 16 + quad * 4;
            ushort4 o;
            unsigned short* po = (unsigned short*)&o;
#pragma unroll
            for (int r = 0; r < 4; ++r) po[r] = f2bf(acc[m][n][r]);
            *(ushort4*)&Ttb[(size_t)col * TP + node] = o;
        }
    }
}

// ---------------------------------------------------------------------------
// Agg GEMM + GraphConv epilogue + FUSED POOL (bf16 MFMA):
//   H = relu(A'@Trel + brel + Troot);  z[g, zoff+c] += scale * sum_rows H
// grid = 1024: branch = blockIdx.x>>9, then g*2 + row-tile.
// ---------------------------------------------------------------------------
__global__ __launch_bounds__(256) void gemm_agg_kernel(const unsigned short* __restrict__ Aall,
                                                       const unsigned short* __restrict__ Tt,
                                                       const float* __restrict__ brel_sc,
                                                       const float* __restrict__ brel_fc,
                                                       unsigned short* __restrict__ Hout,
                                                       float* __restrict__ z,
                                                       int zlayer) {
    __shared__ short As[128 * 40];
    __shared__ short Bs[128 * 40];
    __shared__ float zsum[128];

    const int tid = threadIdx.x;
    const int lane = tid & 63, wid = tid >> 6;
    const int wm = (wid & 1) * 64, wn = (wid >> 1) * 64;
    const int l15 = lane & 15, quad = lane >> 4;
    const int branch = blockIdx.x >> 9;
    const int bx = blockIdx.x & 511;
    const int g = bx >> 1;
    const int row0 = (bx & 1) * 128;
    const unsigned short* Ag = Aall + ((size_t)branch * NG + g) * NPG * APITCH;
    const unsigned short* Ttb = Tt + (size_t)branch * 256 * TP;
    unsigned short* H = Hout + (size_t)branch * NT_T * HDIM;
    const float* brel = branch ? brel_fc : brel_sc;
    const float scale = branch ? 1.0f : (1.0f / 200.0f);
    const int zoff = branch * 256 + zlayer;
    const size_t gnode = (size_t)g * NPG;

    if (tid < 128) zsum[tid] = 0.0f;

    f32x4 acc[4][4];
#pragma unroll
    for (int m = 0; m < 4; ++m)
#pragma unroll
        for (int n = 0; n < 4; ++n)
#pragma unroll
            for (int r = 0; r < 4; ++r) acc[m][n][r] = 0.0f;

    const int r0 = tid >> 2, k0off = (tid & 3) * 8;
    const int r1 = (tid + 256) >> 2, k1off = ((tid + 256) & 3) * 8;

    for (int k0 = 0; k0 < KP1; k0 += 32) {
        uint4 zz; zz.x = zz.y = zz.z = zz.w = 0u;
        uint4 v0 = zz, v1 = zz;
        if (row0 + r0 < NPG) v0 = *(const uint4*)&Ag[(row0 + r0) * APITCH + k0 + k0off];
        if (row0 + r1 < NPG) v1 = *(const uint4*)&Ag[(row0 + r1) * APITCH + k0 + k1off];
        *(uint4*)&As[r0 * 40 + k0off] = v0;
        *(uint4*)&As[r1 * 40 + k1off] = v1;
        // Trel rows 0..127 of T^T; k beyond graph hits A'=0 columns.
        *(uint4*)&Bs[r0 * 40 + k0off] = *(const uint4*)&Ttb[(size_t)r0 * TP + gnode + k0 + k0off];
        *(uint4*)&Bs[r1 * 40 + k1off] = *(const uint4*)&Ttb[(size_t)r1 * TP + gnode + k0 + k1off];
        __syncthreads();

        short8 af[4], bf[4];
#pragma unroll
        for (int m = 0; m < 4; ++m)
            af[m] = *(const short8*)&As[(wm + m * 16 + l15) * 40 + quad * 8];
#pragma unroll
        for (int n = 0; n < 4; ++n)
            bf[n] = *(const short8*)&Bs[(wn + n * 16 + l15) * 40 + quad * 8];
#pragma unroll
        for (int m = 0; m < 4; ++m)
#pragma unroll
            for (int n = 0; n < 4; ++n)
                acc[m][n] = __builtin_amdgcn_mfma_f32_16x16x32_bf16(af[m], bf[n], acc[m][n], 0, 0, 0);
        __syncthreads();
    }

#pragma unroll
    for (int n = 0; n < 4; ++n) {
        int c = wn + n * 16 + l15;
        float bb = brel[c];
        float colsum = 0.0f;
#pragma unroll
        for (int m = 0; m < 4; ++m) {
            int gr = row0 + wm + m * 16 + quad * 4;
            if (gr >= NPG) continue;
            size_t nodeb = gnode + gr;
            ushort4 rt = *(const ushort4*)&Ttb[(size_t)(128 + c) * TP + nodeb];  // Troot
            const unsigned short* prt = (const unsigned short*)&rt;
#pragma unroll
            for (int r = 0; r < 4; ++r) {
                float v = fmaxf(acc[m][n][r] + bb + bf2f(prt[r]), 0.0f);
                H[(nodeb + r) * HDIM + c] = f2bf(v);
                colsum += v;
            }
        }
        atomicAdd(&zsum[c], colsum);
    }
    __syncthreads();
    if (tid < 128) atomicAdd(&z[(size_t)g * 512 + zoff + tid], zsum[tid] * scale);
}

// ---------------------------------------------------------------------------
// MLP head (fp32): z[512] -> relu(lin1)[128] -> relu(lin2)[64] -> lin3[2]
// -> log_softmax. One block per graph.
// ---------------------------------------------------------------------------
__global__ __launch_bounds__(128) void mlp_kernel(const float* __restrict__ z,
                                                  const float* __restrict__ w1, const float* __restrict__ b1,
                                                  const float* __restrict__ w2, const float* __restrict__ b2,
                                                  const float* __restrict__ w3, const float* __restrict__ b3,
                                                  float* __restrict__ out) {
    __shared__ float zs[512];
    __shared__ float l1[128];
    __shared__ float l2[64];
    __shared__ float logits[2];
    int g = blockIdx.x, t = threadIdx.x;

#pragma unroll
    for (int i = 0; i < 4; ++i) zs[t + 128 * i] = z[(size_t)g * 512 + t + 128 * i];
    __syncthreads();

    float s = b1[t];
#pragma unroll 8
    for (int k = 0; k < 512; ++k) s = fmaf(zs[k], w1[k * 128 + t], s);
    l1[t] = fmaxf(s, 0.0f);
    __syncthreads();

    if (t < 64) {
        float s2 = b2[t];
#pragma unroll 8
        for (int k = 0; k < 128; ++k) s2 = fmaf(l1[k], w2[k * 64 + t], s2);
        l2[t] = fmaxf(s2, 0.0f);
    }
    __syncthreads();

    if (t < 2) {
        float s3 = b3[t];
        for (int k = 0; k < 64; ++k) s3 = fmaf(l2[k], w3[k * 2 + t], s3);
        logits[t] = s3;
    }
    __syncthreads();

    if (t < 2) {
        float m = fmaxf(logits[0], logits[1]);
        float lse = m + logf(expf(logits[0] - m) + expf(logits[1] - m));
        out[(size_t)g * 2 + t] = logits[t] - lse;
    }
}

// ---------------------------------------------------------------------------
extern "C" void kernel_launch(void* const* d_in, const int* in_sizes, int n_in,
                              void* d_out, int out_size, void* d_ws, size_t ws_size,
                              hipStream_t stream) {
    const float* sc_x = (const float*)d_in[0];
    const float* fc_x = (const float*)d_in[1];
    const int* sc_ei  = (const int*)d_in[2];
    const int* fc_ei  = (const int*)d_in[3];
    const float* sc1_wrel = (const float*)d_in[5];
    const float* sc1_brel = (const float*)d_in[6];
    const float* sc1_wroot = (const float*)d_in[7];
    const float* sc2_wrel = (const float*)d_in[8];
    const float* sc2_brel = (const float*)d_in[9];
    const float* sc2_wroot = (const float*)d_in[10];
    const float* fc1_wrel = (const float*)d_in[11];
    const float* fc1_brel = (const float*)d_in[12];
    const float* fc1_wroot = (const float*)d_in[13];
    const float* fc2_wrel = (const float*)d_in[14];
    const float* fc2_brel = (const float*)d_in[15];
    const float* fc2_wroot = (const float*)d_in[16];
    const float* lin1_w = (const float*)d_in[17];
    const float* lin1_b = (const float*)d_in[18];
    const float* lin2_w = (const float*)d_in[19];
    const float* lin2_b = (const float*)d_in[20];
    const float* lin3_w = (const float*)d_in[21];
    const float* lin3_b = (const float*)d_in[22];

    // Workspace (shorts unless noted):
    unsigned short* Ab = (unsigned short*)d_ws;                 // 2*256*200*224
    unsigned short* Tt = Ab + (size_t)2 * NG * NPG * APITCH;    // 2*256*TP
    unsigned short* h  = Tt + (size_t)2 * 256 * TP;             // 2*51200*128
    unsigned short* Wb = h + (size_t)2 * NT_T * HDIM;           // 2*(W1SZ+W2SZ)
    float* z = (float*)(Wb + (size_t)2 * (W1SZ + W2SZ));        // 256*512 fp32

    build_adj_kernel<<<2 * NG, 256, 0, stream>>>(sc_ei, fc_ei, Ab);
    convert_w_kernel<<<(2 * (W1SZ + W2SZ) + 255) / 256, 256, 0, stream>>>(
        sc1_wrel, sc1_wroot, fc1_wrel, fc1_wroot,
        sc2_wrel, sc2_wroot, fc2_wrel, fc2_wroot, Wb);
    hipMemsetAsync(z, 0, (size_t)NG * 512 * sizeof(float), stream);

    // Layer 1
    gemm_t1_kernel<<<dim3(NT_T / 128, 2, 2), 256, 0, stream>>>(sc_x, fc_x, Wb, Tt);
    gemm_agg_kernel<<<4 * NG, 256, 0, stream>>>(Ab, Tt, sc1_brel, fc1_brel, h, z, 0);

    // Layer 2
    gemm_t2_kernel<<<dim3(NT_T / 128, 2, 2), 256, 0, stream>>>(h, Wb, Tt);
    gemm_agg_kernel<<<4 * NG, 256, 0, stream>>>(Ab, Tt, sc2_brel, fc2_brel, h, z, 128);

    mlp_kernel<<<NG, 128, 0, stream>>>(z, lin1_w, lin1_b, lin2_w, lin2_b,
                                       lin3_w, lin3_b, (float*)d_out);
}

// Round 4
// 328.157 us; speedup vs baseline: 2.4254x; 1.1950x over previous
//
#include <hip/hip_runtime.h>
#include <math.h>

#define NPG   200                 // nodes per graph
#define HDIM  128
#define NG    256
#define NT_T  (NG * NPG)          // 51200
#define EPG_  3200
#define E_T   (NG * EPG_)         // 819200
#define KP1   224                 // layer-1 K (200) padded to mult of 32
#define APITCH 224                // A' row pitch (zero cols >= 200)
#define TTP   232                 // Tt LDS pitch (shorts): 464B = 29*16 (16B-aligned rows),
                                  // bank stride 116 words == 20 mod 32 -> free 2-way
#define W1SZ  (256 * KP1)
#define W2SZ  (256 * HDIM)

typedef short short8 __attribute__((ext_vector_type(8)));
typedef float f32x4  __attribute__((ext_vector_type(4)));

__device__ __forceinline__ unsigned short f2bf(float f) {
    union { float f; unsigned int u; } v; v.f = f;
    unsigned int u = v.u;
    u += 0x7FFFu + ((u >> 16) & 1u);       // RNE
    return (unsigned short)(u >> 16);
}
__device__ __forceinline__ float bf2f(unsigned short b) {
    union { unsigned int u; float f; } v; v.u = ((unsigned int)b) << 16;
    return v.f;
}

// ---------------------------------------------------------------------------
// Both branches: per-graph adjacency via LDS u8 counters ->
// A' = count/max(deg,1) bf16, [branch][g][dst 0..199][src 0..223] (pad zero).
// ---------------------------------------------------------------------------
__global__ __launch_bounds__(256) void build_adj_kernel(const int* __restrict__ sc_ei,
                                                        const int* __restrict__ fc_ei,
                                                        unsigned short* __restrict__ A) {
    __shared__ unsigned int cnt[10000];    // 200*200 u8 counters packed in u32
    __shared__ float invdeg[200];
    const int branch = blockIdx.x >> 8;
    const int g = blockIdx.x & 255, t = threadIdx.x;
    const int* ei = branch ? fc_ei : sc_ei;

    for (int i = t; i < 10000; i += 256) cnt[i] = 0u;
    __syncthreads();

    const int ebase = g * EPG_;
    for (int i = t; i < EPG_; i += 256) {
        int src = ei[ebase + i];
        int dst = ei[E_T + ebase + i];
        int idx = (dst - g * NPG) * NPG + (src - g * NPG);
        atomicAdd(&cnt[idx >> 2], 1u << ((idx & 3) * 8));
    }
    __syncthreads();

    if (t < NPG) {
        unsigned int s = 0;
        for (int w = 0; w < 50; ++w) {
            unsigned int v = cnt[t * 50 + w];
            s += (v & 0xFFu) + ((v >> 8) & 0xFFu) + ((v >> 16) & 0xFFu) + ((v >> 24) & 0xFFu);
        }
        invdeg[t] = 1.0f / fmaxf((float)s, 1.0f);
    }
    __syncthreads();

    unsigned short* Ag = A + ((size_t)branch * NG + g) * NPG * APITCH;
    for (int q = t; q < NPG * (APITCH / 4); q += 256) {
        int row = q / 56;
        int c4  = (q - row * 56) * 4;
        float inv = invdeg[row];
        ushort4 o;
        unsigned short* po = (unsigned short*)&o;
#pragma unroll
        for (int j = 0; j < 4; ++j) {
            int col = c4 + j;
            float v = 0.0f;
            if (col < NPG) {
                unsigned int w = cnt[row * 50 + (col >> 2)];
                v = (float)((w >> ((col & 3) * 8)) & 0xFFu) * inv;
            }
            po[j] = f2bf(v);
        }
        *(ushort4*)&Ag[row * APITCH + c4] = o;
    }
}

// ---------------------------------------------------------------------------
// All 4 weight pairs -> packed W^T bf16: [br0 L1 | br1 L1 | br0 L2 | br1 L2].
// Rows 0..127 = wrel cols, 128..255 = wroot cols; k >= K zero-padded.
// ---------------------------------------------------------------------------
__global__ __launch_bounds__(256) void convert_w_kernel(
        const float* __restrict__ s1r, const float* __restrict__ s1o,
        const float* __restrict__ f1r, const float* __restrict__ f1o,
        const float* __restrict__ s2r, const float* __restrict__ s2o,
        const float* __restrict__ f2r, const float* __restrict__ f2o,
        unsigned short* __restrict__ wb) {
    int idx = blockIdx.x * 256 + threadIdx.x;
    if (idx >= 2 * W1SZ + 2 * W2SZ) return;
    float v = 0.0f;
    if (idx < 2 * W1SZ) {
        int branch = idx / W1SZ, rem = idx - branch * W1SZ;
        int c = rem / KP1, k = rem - c * KP1;
        const float* wr = branch ? f1r : s1r;
        const float* wo = branch ? f1o : s1o;
        if (k < 200) v = (c < 128) ? wr[(size_t)k * 128 + c] : wo[(size_t)k * 128 + (c - 128)];
    } else {
        int i2 = idx - 2 * W1SZ;
        int branch = i2 / W2SZ, rem = i2 - branch * W2SZ;
        int c = rem / HDIM, k = rem - c * HDIM;
        const float* wr = branch ? f2r : s2r;
        const float* wo = branch ? f2o : s2o;
        v = (c < 128) ? wr[(size_t)k * 128 + c] : wo[(size_t)k * 128 + (c - 128)];
    }
    wb[idx] = f2bf(v);
}

// ---------------------------------------------------------------------------
// Fused GraphConv layer: per-block = (col-half, graph, branch).
//   GEMM1: Tt[ch][s] = sum_k X[g*200+s][k] * W[ch][k]    (-> LDS, never HBM)
//   GEMM2: H[d][c]   = relu( sum_s Trel[c][s] A'[d][s] + brel + Troot[d][c] )
//   Pool fused: z[g, branch*256 + layer*128 + half*64 + c] = scale * sum_d H
// Barrier-free K-loops (direct global gathers, fully unrolled); one mid barrier.
// Tt s-pad (s>=200) holds finite garbage, annihilated by A' zero columns.
// ---------------------------------------------------------------------------
template<bool L1>
__global__ __launch_bounds__(256, 2) void layer_kernel(
        const float* __restrict__ x_sc, const float* __restrict__ x_fc,
        const unsigned short* __restrict__ hin,
        const unsigned short* __restrict__ Wall,
        const unsigned short* __restrict__ Aall,
        const float* __restrict__ brel_sc, const float* __restrict__ brel_fc,
        unsigned short* __restrict__ Hout,
        float* __restrict__ z, int zlayer) {
    __shared__ alignas(16) short Tt[128 * TTP];   // 59,392 B
    __shared__ float zsum[64];

    const int tid = threadIdx.x;
    const int lane = tid & 63, wid = tid >> 6;
    const int l15 = lane & 15, quad = lane >> 4;
    const int half = blockIdx.x;          // 0/1: T cols [h*64, h*64+64) rel+root
    const int g = blockIdx.y, branch = blockIdx.z;

    if (tid < 64) zsum[tid] = 0.0f;

    const int KITER = L1 ? 7 : 4;
    const int KX    = L1 ? 200 : 128;     // input row pitch
    const int WP    = L1 ? KP1 : HDIM;    // packed-W row pitch
    const unsigned short* W = Wall + (L1 ? (size_t)branch * W1SZ
                                         : (size_t)2 * W1SZ + (size_t)branch * W2SZ);

    // ======== GEMM1: M = s (14 tiles), N = ch (8 tiles); wave 7m x 4n ========
    const int sm = wid & 1, sn = wid >> 1;

    int xoff[7];                          // row*KX + quad*8 (row clamped)
#pragma unroll
    for (int mt = 0; mt < 7; ++mt) {
        int s = (sm * 7 + mt) * 16 + l15;
        int row = g * NPG + s;
        if (row > NT_T - 1) row = NT_T - 1;
        xoff[mt] = row * KX + quad * 8;
    }
    int wrow[4], trow[4];
#pragma unroll
    for (int nt = 0; nt < 4; ++nt) {
        int i = sn * 64 + nt * 16 + l15;          // local T row 0..127
        trow[nt] = i;
        wrow[nt] = half * 64 + sn * 128 + nt * 16 + l15;  // packed-W row
    }

    f32x4 acc[7][4];
#pragma unroll
    for (int mt = 0; mt < 7; ++mt)
#pragma unroll
        for (int nt = 0; nt < 4; ++nt)
#pragma unroll
            for (int r = 0; r < 4; ++r) acc[mt][nt][r] = 0.0f;

    const float* X32 = branch ? x_fc : x_sc;
    const unsigned short* X16 = hin + (size_t)branch * NT_T * HDIM;

#pragma unroll
    for (int ki = 0; ki < KITER; ++ki) {
        const int kbase = ki * 32;
        short8 af[7];
#pragma unroll
        for (int mt = 0; mt < 7; ++mt) {
            if (L1) {
                int a = xoff[mt] + kbase;
                if (a > NT_T * 200 - 8) a = NT_T * 200 - 8;   // finite garbage * W-pad0
                float4 p0 = *(const float4*)&X32[a];
                float4 p1 = *(const float4*)&X32[a + 4];
                union { short8 s; unsigned int u[4]; } pk;
                pk.u[0] = (unsigned)f2bf(p0.x) | ((unsigned)f2bf(p0.y) << 16);
                pk.u[1] = (unsigned)f2bf(p0.z) | ((unsigned)f2bf(p0.w) << 16);
                pk.u[2] = (unsigned)f2bf(p1.x) | ((unsigned)f2bf(p1.y) << 16);
                pk.u[3] = (unsigned)f2bf(p1.z) | ((unsigned)f2bf(p1.w) << 16);
                af[mt] = pk.s;
            } else {
                af[mt] = *(const short8*)&X16[xoff[mt] + kbase];
            }
        }
        short8 bf[4];
#pragma unroll
        for (int nt = 0; nt < 4; ++nt)
            bf[nt] = *(const short8*)&W[(size_t)wrow[nt] * WP + kbase + quad * 8];
#pragma unroll
        for (int mt = 0; mt < 7; ++mt)
#pragma unroll
            for (int nt = 0; nt < 4; ++nt)
                acc[mt][nt] = __builtin_amdgcn_mfma_f32_16x16x32_bf16(af[mt], bf[nt], acc[mt][nt], 0, 0, 0);
    }

    // D rows = s (quad*4+r): 4 s-consecutive bf16 -> one ds_write_b64
#pragma unroll
    for (int mt = 0; mt < 7; ++mt) {
        int s0 = (sm * 7 + mt) * 16 + quad * 4;
#pragma unroll
        for (int nt = 0; nt < 4; ++nt) {
            ushort4 o;
            unsigned short* po = (unsigned short*)&o;
#pragma unroll
            for (int r = 0; r < 4; ++r) po[r] = f2bf(acc[mt][nt][r]);
            *(ushort4*)&Tt[trow[nt] * TTP + s0] = o;
        }
    }
    __syncthreads();

    // ======== GEMM2: M = c (4 tiles, 64 ch), N = d (14 tiles); wave 2m x 7n ==
    const int wm2 = wid & 1, wn2 = wid >> 1;
    const unsigned short* Ag = Aall + ((size_t)branch * NG + g) * NPG * APITCH;

    int drow[7];
#pragma unroll
    for (int nt = 0; nt < 7; ++nt) drow[nt] = (wn2 * 7 + nt) * 16 + l15;
    int crow[2];
#pragma unroll
    for (int mt = 0; mt < 2; ++mt) crow[mt] = (wm2 * 2 + mt) * 16 + l15;

    f32x4 acc2[2][7];
#pragma unroll
    for (int mt = 0; mt < 2; ++mt)
#pragma unroll
        for (int nt = 0; nt < 7; ++nt)
#pragma unroll
            for (int r = 0; r < 4; ++r) acc2[mt][nt][r] = 0.0f;

#pragma unroll
    for (int ki = 0; ki < 7; ++ki) {
        const int k0 = ki * 32 + quad * 8;
        short8 a2[2];
#pragma unroll
        for (int mt = 0; mt < 2; ++mt)
            a2[mt] = *(const short8*)&Tt[crow[mt] * TTP + k0];    // Trel rows 0..63
        short8 b2[7];
#pragma unroll
        for (int nt = 0; nt < 7; ++nt)
            b2[nt] = *(const short8*)&Ag[(size_t)drow[nt] * APITCH + k0];
#pragma unroll
        for (int mt = 0; mt < 2; ++mt)
#pragma unroll
            for (int nt = 0; nt < 7; ++nt)
                acc2[mt][nt] = __builtin_amdgcn_mfma_f32_16x16x32_bf16(a2[mt], b2[nt], acc2[mt][nt], 0, 0, 0);
    }

    const float* brel = branch ? brel_fc : brel_sc;
    unsigned short* Hb = Hout + (size_t)branch * NT_T * HDIM;
    float part[2][4];
    float bb[2][4];
#pragma unroll
    for (int mt = 0; mt < 2; ++mt)
#pragma unroll
        for (int r = 0; r < 4; ++r) {
            bb[mt][r] = brel[half * 64 + (wm2 * 2 + mt) * 16 + quad * 4 + r];
            part[mt][r] = 0.0f;
        }

#pragma unroll
    for (int mt = 0; mt < 2; ++mt) {
        const int c0 = (wm2 * 2 + mt) * 16 + quad * 4;   // local ch 0..63
#pragma unroll
        for (int nt = 0; nt < 7; ++nt) {
            const int d = drow[nt];
            if (d < NPG) {
                size_t node = (size_t)g * NPG + d;
                ushort4 o;
                unsigned short* po = (unsigned short*)&o;
#pragma unroll
                for (int r = 0; r < 4; ++r) {
                    float v = acc2[mt][nt][r] + bb[mt][r]
                            + bf2f((unsigned short)Tt[(64 + c0 + r) * TTP + d]);  // Troot
                    v = fmaxf(v, 0.0f);
                    part[mt][r] += v;
                    po[r] = f2bf(v);
                }
                if (L1) *(ushort4*)&Hb[node * HDIM + half * 64 + c0] = o;  // L2: pool only
            }
        }
    }

    // butterfly over the 16 l15 lanes (bits 0..3), then one LDS atomic per group
#pragma unroll
    for (int mt = 0; mt < 2; ++mt)
#pragma unroll
        for (int r = 0; r < 4; ++r) {
            float v = part[mt][r];
            v += __shfl_xor(v, 1);
            v += __shfl_xor(v, 2);
            v += __shfl_xor(v, 4);
            v += __shfl_xor(v, 8);
            if (l15 == 0)
                atomicAdd(&zsum[(wm2 * 2 + mt) * 16 + quad * 4 + r], v);
        }
    __syncthreads();

    if (tid < 64)
        z[(size_t)g * 512 + branch * 256 + zlayer + half * 64 + tid] =
            zsum[tid] * (branch ? 1.0f : (1.0f / 200.0f));
}

// ---------------------------------------------------------------------------
// MLP head (fp32): z[512] -> relu(lin1)[128] -> relu(lin2)[64] -> lin3[2]
// -> log_softmax. One block per graph.
// ---------------------------------------------------------------------------
__global__ __launch_bounds__(128) void mlp_kernel(const float* __restrict__ z,
                                                  const float* __restrict__ w1, const float* __restrict__ b1,
                                                  const float* __restrict__ w2, const float* __restrict__ b2,
                                                  const float* __restrict__ w3, const float* __restrict__ b3,
                                                  float* __restrict__ out) {
    __shared__ float zs[512];
    __shared__ float l1[128];
    __shared__ float l2[64];
    __shared__ float logits[2];
    int g = blockIdx.x, t = threadIdx.x;

#pragma unroll
    for (int i = 0; i < 4; ++i) zs[t + 128 * i] = z[(size_t)g * 512 + t + 128 * i];
    __syncthreads();

    float s = b1[t];
#pragma unroll 8
    for (int k = 0; k < 512; ++k) s = fmaf(zs[k], w1[k * 128 + t], s);
    l1[t] = fmaxf(s, 0.0f);
    __syncthreads();

    if (t < 64) {
        float s2 = b2[t];
#pragma unroll 8
        for (int k = 0; k < 128; ++k) s2 = fmaf(l1[k], w2[k * 64 + t], s2);
        l2[t] = fmaxf(s2, 0.0f);
    }
    __syncthreads();

    if (t < 2) {
        float s3 = b3[t];
        for (int k = 0; k < 64; ++k) s3 = fmaf(l2[k], w3[k * 2 + t], s3);
        logits[t] = s3;
    }
    __syncthreads();

    if (t < 2) {
        float m = fmaxf(logits[0], logits[1]);
        float lse = m + logf(expf(logits[0] - m) + expf(logits[1] - m));
        out[(size_t)g * 2 + t] = logits[t] - lse;
    }
}

// ---------------------------------------------------------------------------
extern "C" void kernel_launch(void* const* d_in, const int* in_sizes, int n_in,
                              void* d_out, int out_size, void* d_ws, size_t ws_size,
                              hipStream_t stream) {
    const float* sc_x = (const float*)d_in[0];
    const float* fc_x = (const float*)d_in[1];
    const int* sc_ei  = (const int*)d_in[2];
    const int* fc_ei  = (const int*)d_in[3];
    const float* sc1_wrel = (const float*)d_in[5];
    const float* sc1_brel = (const float*)d_in[6];
    const float* sc1_wroot = (const float*)d_in[7];
    const float* sc2_wrel = (const float*)d_in[8];
    const float* sc2_brel = (const float*)d_in[9];
    const float* sc2_wroot = (const float*)d_in[10];
    const float* fc1_wrel = (const float*)d_in[11];
    const float* fc1_brel = (const float*)d_in[12];
    const float* fc1_wroot = (const float*)d_in[13];
    const float* fc2_wrel = (const float*)d_in[14];
    const float* fc2_brel = (const float*)d_in[15];
    const float* fc2_wroot = (const float*)d_in[16];
    const float* lin1_w = (const float*)d_in[17];
    const float* lin1_b = (const float*)d_in[18];
    const float* lin2_w = (const float*)d_in[19];
    const float* lin2_b = (const float*)d_in[20];
    const float* lin3_w = (const float*)d_in[21];
    const float* lin3_b = (const float*)d_in[22];

    // Workspace (shorts unless noted): A' | h | W | z   (~73 MB)
    unsigned short* Ab = (unsigned short*)d_ws;                 // 2*256*200*224
    unsigned short* h  = Ab + (size_t)2 * NG * NPG * APITCH;    // 2*51200*128
    unsigned short* Wb = h + (size_t)2 * NT_T * HDIM;           // 2*(W1SZ+W2SZ)
    float* z = (float*)(Wb + (size_t)2 * (W1SZ + W2SZ));        // 256*512 fp32

    build_adj_kernel<<<2 * NG, 256, 0, stream>>>(sc_ei, fc_ei, Ab);
    convert_w_kernel<<<(2 * (W1SZ + W2SZ) + 255) / 256, 256, 0, stream>>>(
        sc1_wrel, sc1_wroot, fc1_wrel, fc1_wroot,
        sc2_wrel, sc2_wroot, fc2_wrel, fc2_wroot, Wb);

    layer_kernel<true><<<dim3(2, NG, 2), 256, 0, stream>>>(
        sc_x, fc_x, h, Wb, Ab, sc1_brel, fc1_brel, h, z, 0);
    layer_kernel<false><<<dim3(2, NG, 2), 256, 0, stream>>>(
        sc_x, fc_x, h, Wb, Ab, sc2_brel, fc2_brel, h, z, 128);

    mlp_kernel<<<NG, 128, 0, stream>>>(z, lin1_w, lin1_b, lin2_w, lin2_b,
                                       lin3_w, lin3_b, (float*)d_out);
}